// Round 1
// baseline (704.712 us; speedup 1.0000x reference)
//
#include <hip/hip_runtime.h>

#define HDIM 256            // feature dim, fixed by the reference
#define ROWS_PER_WAVE 128   // rows of x each wave reduces
#define GEMM_ROWS 16        // segment-rows per block in the output GEMM

// ---------------------------------------------------------------------------
// Kernel 1: segment-sum of x rows (sorted seg_ids) -> pooled[B][H], counts[B]
// One wave (64 lanes) owns ROWS_PER_WAVE contiguous rows; each lane holds a
// float4 accumulator (cols lane*4 .. lane*4+3). Flush with atomics only at
// segment boundaries / chunk edges (runs average ~488 rows -> rare).
// ---------------------------------------------------------------------------
__global__ __launch_bounds__(256) void seg_pool_kernel(
    const float* __restrict__ x, const int* __restrict__ seg,
    float* __restrict__ pooled, float* __restrict__ counts, int N)
{
    const int wave = blockIdx.x * (blockDim.x >> 6) + (threadIdx.x >> 6);
    const int lane = threadIdx.x & 63;

    long r0 = (long)wave * ROWS_PER_WAVE;
    if (r0 >= N) return;
    long r1 = r0 + ROWS_PER_WAVE;
    if (r1 > N) r1 = N;

    float4 acc = make_float4(0.f, 0.f, 0.f, 0.f);
    int cur = seg[r0];
    int cnt = 0;

    long r = r0;
    while (r < r1) {
        // fast path: 4 rows, all in the current segment (wave-uniform branch)
        if (r + 4 <= r1) {
            int sA = seg[r];
            int sB = seg[r + 3];
            if (sA == cur && sB == cur) {
                const float4* p = (const float4*)(x + r * HDIM) + lane;
                float4 v0 = p[0];            // row r   (row stride = 64 float4)
                float4 v1 = p[64];           // row r+1
                float4 v2 = p[128];          // row r+2
                float4 v3 = p[192];          // row r+3
                acc.x += (v0.x + v1.x) + (v2.x + v3.x);
                acc.y += (v0.y + v1.y) + (v2.y + v3.y);
                acc.z += (v0.z + v1.z) + (v2.z + v3.z);
                acc.w += (v0.w + v1.w) + (v2.w + v3.w);
                cnt += 4;
                r += 4;
                continue;
            }
        }
        // slow path: single row, may cross a segment boundary
        int s = seg[r];
        if (s != cur) {
            float* dst = pooled + (long)cur * HDIM + lane * 4;
            atomicAdd(dst + 0, acc.x);
            atomicAdd(dst + 1, acc.y);
            atomicAdd(dst + 2, acc.z);
            atomicAdd(dst + 3, acc.w);
            if (lane == 0) atomicAdd(&counts[cur], (float)cnt);
            acc = make_float4(0.f, 0.f, 0.f, 0.f);
            cnt = 0;
            cur = s;
        }
        const float4* p = (const float4*)(x + r * HDIM) + lane;
        float4 v = *p;
        acc.x += v.x; acc.y += v.y; acc.z += v.z; acc.w += v.w;
        ++cnt;
        ++r;
    }
    if (cnt > 0) {
        float* dst = pooled + (long)cur * HDIM + lane * 4;
        atomicAdd(dst + 0, acc.x);
        atomicAdd(dst + 1, acc.y);
        atomicAdd(dst + 2, acc.z);
        atomicAdd(dst + 3, acc.w);
        if (lane == 0) atomicAdd(&counts[cur], (float)cnt);
    }
}

// ---------------------------------------------------------------------------
// Kernel 2: W[H][H] -> Wt[H][H] (transpose) so the GEMM reads W coalesced.
// Classic 32x32 LDS tile transpose, block = 256 threads (32x8), grid 8x8.
// ---------------------------------------------------------------------------
__global__ __launch_bounds__(256) void transpose_kernel(
    const float* __restrict__ W, float* __restrict__ Wt)
{
    __shared__ float tile[32][33];  // +1 pad: no bank conflicts on transposed read
    const int tx = threadIdx.x & 31;
    const int ty = threadIdx.x >> 5;          // 0..7
    const int bx = blockIdx.x;                // tile col in W
    const int by = blockIdx.y;                // tile row in W
#pragma unroll
    for (int i = 0; i < 32; i += 8)
        tile[ty + i][tx] = W[(by * 32 + ty + i) * HDIM + bx * 32 + tx];
    __syncthreads();
#pragma unroll
    for (int i = 0; i < 32; i += 8)
        Wt[(bx * 32 + ty + i) * HDIM + by * 32 + tx] = tile[tx][ty + i];
}

// ---------------------------------------------------------------------------
// Kernel 3: out[B][H] = relu(pooled @ W^T + counts*b)
//           = relu( sum_k pooled[row][k] * Wt[k][col] + counts[row]*b[col] )
// Block: 256 threads (one col each) x GEMM_ROWS rows. pooled rows staged in
// LDS (same-address broadcast reads in k-loop -> conflict-free). Wt reads
// coalesced; 64 blocks x 256 KB streams from L2.
// ---------------------------------------------------------------------------
__global__ __launch_bounds__(256) void out_gemm_kernel(
    const float* __restrict__ pooled, const float* __restrict__ Wt,
    const float* __restrict__ bias, const float* __restrict__ counts,
    float* __restrict__ out, int B)
{
    __shared__ float sp[GEMM_ROWS][HDIM];  // 16 KB
    const int col = threadIdx.x;
    const int r0 = blockIdx.x * GEMM_ROWS;
    const int rmax = (B - r0 < GEMM_ROWS) ? (B - r0) : GEMM_ROWS;

    for (int r = 0; r < rmax; ++r)
        sp[r][col] = pooled[(long)(r0 + r) * HDIM + col];
    __syncthreads();

    float acc[GEMM_ROWS];
#pragma unroll
    for (int r = 0; r < GEMM_ROWS; ++r) acc[r] = 0.f;

    for (int k = 0; k < HDIM; ++k) {
        float w = Wt[(long)k * HDIM + col];
#pragma unroll
        for (int r = 0; r < GEMM_ROWS; ++r)
            acc[r] = fmaf(sp[r][k], w, acc[r]);
    }

    float bv = bias[col];
    for (int r = 0; r < rmax; ++r) {
        float v = acc[r] + counts[r0 + r] * bv;
        out[(long)(r0 + r) * HDIM + col] = fmaxf(v, 0.f);
    }
}

// ---------------------------------------------------------------------------
// Launch
// inputs: d_in[0]=x (f32, N*H), d_in[1]=seg_ids (i32, N), d_in[2]=W (f32, H*H),
//         d_in[3]=b (f32, H), d_in[4]=num_segments (i32 scalar, device-side)
// out: f32 [B][H];  B derived as out_size / H (can't read device scalar here).
// ws layout: pooled (B*H f32) | counts (B f32) | Wt (H*H f32)
// ---------------------------------------------------------------------------
extern "C" void kernel_launch(void* const* d_in, const int* in_sizes, int n_in,
                              void* d_out, int out_size, void* d_ws, size_t ws_size,
                              hipStream_t stream)
{
    const float* x   = (const float*)d_in[0];
    const int*   seg = (const int*)d_in[1];
    const float* W   = (const float*)d_in[2];
    const float* b   = (const float*)d_in[3];
    float*       out = (float*)d_out;

    const int N = in_sizes[0] / HDIM;
    const int B = out_size / HDIM;

    float* pooled = (float*)d_ws;
    float* counts = pooled + (size_t)B * HDIM;
    float* Wt     = counts + B;

    // zero the atomic accumulators (ws is poisoned 0xAA before every launch)
    hipMemsetAsync(d_ws, 0, ((size_t)B * HDIM + B) * sizeof(float), stream);

    // segment pooling: one wave per ROWS_PER_WAVE rows, 4 waves per block
    const int waves  = (N + ROWS_PER_WAVE - 1) / ROWS_PER_WAVE;
    const int blocks = (waves + 3) / 4;
    seg_pool_kernel<<<blocks, 256, 0, stream>>>(x, seg, pooled, counts, N);

    // W transpose (independent of pooling, but same stream keeps it simple)
    transpose_kernel<<<dim3(HDIM / 32, HDIM / 32), 256, 0, stream>>>(W, Wt);

    // tiny output GEMM + bias*count + relu
    const int gblocks = (B + GEMM_ROWS - 1) / GEMM_ROWS;
    out_gemm_kernel<<<gblocks, 256, 0, stream>>>(pooled, Wt, b, counts, out, B);
}

// Round 2
// 681.767 us; speedup vs baseline: 1.0337x; 1.0337x over previous
//
#include <hip/hip_runtime.h>

#define HDIM 256            // feature dim, fixed by the reference
#define ROWS_PER_WAVE 128   // rows of x each wave reduces
#define GEMM_ROWS 4         // segment-rows per block in the output GEMM

// ---------------------------------------------------------------------------
// flush helper: one wave's float4 accumulator (cols lane*4..lane*4+3) into
// pooled[segid][:] plus the row count into counts[segid].
// ---------------------------------------------------------------------------
__device__ __forceinline__ void flush_acc(float* __restrict__ pooled,
                                          float* __restrict__ counts,
                                          int segid, int lane,
                                          const float4& acc, int cnt)
{
    float* dst = pooled + (long)segid * HDIM + lane * 4;
    atomicAdd(dst + 0, acc.x);
    atomicAdd(dst + 1, acc.y);
    atomicAdd(dst + 2, acc.z);
    atomicAdd(dst + 3, acc.w);
    if (lane == 0) atomicAdd(&counts[segid], (float)cnt);
}

// ---------------------------------------------------------------------------
// Kernel 1: segment-sum of x rows (sorted seg_ids) -> pooled[B][H], counts[B]
// One wave owns 128 contiguous rows. Chunk seg-ids preloaded into 2 regs/lane
// (2 coalesced loads); single-segment chunks (~74%) take a branch-free 8-row
// unrolled loop; boundary chunks read seg ids via __shfl (no memory).
// ---------------------------------------------------------------------------
__global__ __launch_bounds__(256) void seg_pool_kernel(
    const float* __restrict__ x, const int* __restrict__ seg,
    float* __restrict__ pooled, float* __restrict__ counts, int N)
{
    const int wave = blockIdx.x * 4 + (threadIdx.x >> 6);
    const int lane = threadIdx.x & 63;

    long r0 = (long)wave * ROWS_PER_WAVE;
    if (r0 >= N) return;
    long r1 = r0 + ROWS_PER_WAVE;
    if (r1 > N) r1 = N;
    const int nrows = (int)(r1 - r0);

    // preload this chunk's seg ids: lane j holds seg[r0+j] and seg[r0+64+j]
    long i0 = r0 + lane;       if (i0 >= N) i0 = N - 1;
    long i1 = r0 + 64 + lane;  if (i1 >= N) i1 = N - 1;
    const int sv0 = seg[i0];
    const int sv1 = seg[i1];
    const int sfirst = __shfl(sv0, 0);
    const int slast  = (nrows <= 64) ? __shfl(sv0, nrows - 1)
                                     : __shfl(sv1, nrows - 1 - 64);

    const float4* xp = (const float4*)x + r0 * 64 + lane;  // row stride = 64 float4

    float4 acc = make_float4(0.f, 0.f, 0.f, 0.f);

    if (sfirst == slast) {
        // whole chunk in one segment: branch-free, 8 loads in flight
        int rr = 0;
        for (; rr + 8 <= nrows; rr += 8) {
            float4 v0 = xp[(rr + 0) * 64];
            float4 v1 = xp[(rr + 1) * 64];
            float4 v2 = xp[(rr + 2) * 64];
            float4 v3 = xp[(rr + 3) * 64];
            float4 v4 = xp[(rr + 4) * 64];
            float4 v5 = xp[(rr + 5) * 64];
            float4 v6 = xp[(rr + 6) * 64];
            float4 v7 = xp[(rr + 7) * 64];
            acc.x += ((v0.x + v1.x) + (v2.x + v3.x)) + ((v4.x + v5.x) + (v6.x + v7.x));
            acc.y += ((v0.y + v1.y) + (v2.y + v3.y)) + ((v4.y + v5.y) + (v6.y + v7.y));
            acc.z += ((v0.z + v1.z) + (v2.z + v3.z)) + ((v4.z + v5.z) + (v6.z + v7.z));
            acc.w += ((v0.w + v1.w) + (v2.w + v3.w)) + ((v4.w + v5.w) + (v6.w + v7.w));
        }
        for (; rr < nrows; ++rr) {
            float4 v = xp[rr * 64];
            acc.x += v.x; acc.y += v.y; acc.z += v.z; acc.w += v.w;
        }
        flush_acc(pooled, counts, sfirst, lane, acc, nrows);
    } else {
        // chunk crosses >=1 boundary: seg ids come from registers via shfl
        int cur = sfirst;
        int cnt = 0;
        int rr  = 0;
        while (rr < nrows) {
            int s_r = (rr < 64) ? __shfl(sv0, rr) : __shfl(sv1, rr - 64);
            if (s_r != cur) {
                flush_acc(pooled, counts, cur, lane, acc, cnt);
                acc = make_float4(0.f, 0.f, 0.f, 0.f);
                cnt = 0;
                cur = s_r;
            }
            if (rr + 4 <= nrows) {
                int s_3 = (rr + 3 < 64) ? __shfl(sv0, rr + 3) : __shfl(sv1, rr + 3 - 64);
                if (s_3 == cur) {   // sorted => rows rr..rr+3 all in cur
                    float4 v0 = xp[(rr + 0) * 64];
                    float4 v1 = xp[(rr + 1) * 64];
                    float4 v2 = xp[(rr + 2) * 64];
                    float4 v3 = xp[(rr + 3) * 64];
                    acc.x += (v0.x + v1.x) + (v2.x + v3.x);
                    acc.y += (v0.y + v1.y) + (v2.y + v3.y);
                    acc.z += (v0.z + v1.z) + (v2.z + v3.z);
                    acc.w += (v0.w + v1.w) + (v2.w + v3.w);
                    cnt += 4; rr += 4;
                    continue;
                }
            }
            float4 v = xp[rr * 64];
            acc.x += v.x; acc.y += v.y; acc.z += v.z; acc.w += v.w;
            ++cnt; ++rr;
        }
        flush_acc(pooled, counts, cur, lane, acc, cnt);
    }
}

// ---------------------------------------------------------------------------
// Kernel 0 (prep): transpose W -> Wt AND zero pooled/counts (fused; removes
// the separate memset dispatch). Grid 8x8, block 256 (32x8 tile threads).
// zero region is (B*H + B) floats, float4-stored, grid-strided.
// ---------------------------------------------------------------------------
__global__ __launch_bounds__(256) void prep_kernel(
    const float* __restrict__ W, float* __restrict__ Wt,
    float4* __restrict__ zero_dst, int zero_count4)
{
    __shared__ float tile[32][33];  // +1 pad: conflict-free transposed read
    const int tx = threadIdx.x & 31;
    const int ty = threadIdx.x >> 5;
    const int bx = blockIdx.x;
    const int by = blockIdx.y;
#pragma unroll
    for (int i = 0; i < 32; i += 8)
        tile[ty + i][tx] = W[(by * 32 + ty + i) * HDIM + bx * 32 + tx];

    // zero pooled+counts while the tile loads settle
    const int gtid = (blockIdx.y * gridDim.x + blockIdx.x) * 256 + threadIdx.x;
    const int nth  = gridDim.x * gridDim.y * 256;
    const float4 z = make_float4(0.f, 0.f, 0.f, 0.f);
    for (int i = gtid; i < zero_count4; i += nth) zero_dst[i] = z;

    __syncthreads();
#pragma unroll
    for (int i = 0; i < 32; i += 8)
        Wt[(bx * 32 + ty + i) * HDIM + by * 32 + tx] = tile[tx][ty + i];
}

// ---------------------------------------------------------------------------
// Kernel 2: out[B][H] = relu(pooled @ W^T + counts*b)
// 4 rows x 256 cols per block, 256 blocks -> every CU busy. pooled rows in
// LDS (float4 broadcast reads), Wt streamed coalesced from L2, k unrolled x4.
// ---------------------------------------------------------------------------
__global__ __launch_bounds__(256) void out_gemm_kernel(
    const float* __restrict__ pooled, const float* __restrict__ Wt,
    const float* __restrict__ bias, const float* __restrict__ counts,
    float* __restrict__ out, int B)
{
    __shared__ float sp[GEMM_ROWS][HDIM];  // 4 KB
    const int col = threadIdx.x;
    const int r0  = blockIdx.x * GEMM_ROWS;
    const int rmax = (B - r0 < GEMM_ROWS) ? (B - r0) : GEMM_ROWS;

    // stage 4 rows (4 KB) with one float4 per thread
    {
        const float4* src = (const float4*)(pooled + (long)r0 * HDIM);
        float4* dst = (float4*)&sp[0][0];
        int lim = rmax * (HDIM / 4);
        dst[col] = (col < lim) ? src[col] : make_float4(0.f, 0.f, 0.f, 0.f);
    }
    __syncthreads();

    float a0 = 0.f, a1 = 0.f, a2 = 0.f, a3 = 0.f;
    for (int k = 0; k < HDIM; k += 4) {
        float w0 = Wt[(long)(k + 0) * HDIM + col];
        float w1 = Wt[(long)(k + 1) * HDIM + col];
        float w2 = Wt[(long)(k + 2) * HDIM + col];
        float w3 = Wt[(long)(k + 3) * HDIM + col];
        float4 s0 = *(const float4*)&sp[0][k];
        float4 s1 = *(const float4*)&sp[1][k];
        float4 s2 = *(const float4*)&sp[2][k];
        float4 s3 = *(const float4*)&sp[3][k];
        a0 = fmaf(s0.x, w0, a0); a0 = fmaf(s0.y, w1, a0); a0 = fmaf(s0.z, w2, a0); a0 = fmaf(s0.w, w3, a0);
        a1 = fmaf(s1.x, w0, a1); a1 = fmaf(s1.y, w1, a1); a1 = fmaf(s1.z, w2, a1); a1 = fmaf(s1.w, w3, a1);
        a2 = fmaf(s2.x, w0, a2); a2 = fmaf(s2.y, w1, a2); a2 = fmaf(s2.z, w2, a2); a2 = fmaf(s2.w, w3, a2);
        a3 = fmaf(s3.x, w0, a3); a3 = fmaf(s3.y, w1, a3); a3 = fmaf(s3.z, w2, a3); a3 = fmaf(s3.w, w3, a3);
    }

    const float bv = bias[col];
    float accs[GEMM_ROWS] = {a0, a1, a2, a3};
    for (int r = 0; r < rmax; ++r) {
        float v = accs[r] + counts[r0 + r] * bv;
        out[(long)(r0 + r) * HDIM + col] = fmaxf(v, 0.f);
    }
}

// ---------------------------------------------------------------------------
// Launch.  ws layout: pooled (B*H f32) | counts (B f32) | Wt (H*H f32)
// ---------------------------------------------------------------------------
extern "C" void kernel_launch(void* const* d_in, const int* in_sizes, int n_in,
                              void* d_out, int out_size, void* d_ws, size_t ws_size,
                              hipStream_t stream)
{
    const float* x   = (const float*)d_in[0];
    const int*   seg = (const int*)d_in[1];
    const float* W   = (const float*)d_in[2];
    const float* b   = (const float*)d_in[3];
    float*       out = (float*)d_out;

    const int N = in_sizes[0] / HDIM;
    const int B = out_size / HDIM;

    float* pooled = (float*)d_ws;
    float* counts = pooled + (size_t)B * HDIM;
    float* Wt     = counts + B;

    // prep: transpose W + zero pooled/counts  (must precede seg_pool; same stream)
    const int zero_count4 = (B * HDIM + B) / 4;   // both divisible by 4
    prep_kernel<<<dim3(HDIM / 32, HDIM / 32), 256, 0, stream>>>(
        W, Wt, (float4*)d_ws, zero_count4);

    // segment pooling: one wave per 128 rows, 4 waves per block
    const int waves  = (N + ROWS_PER_WAVE - 1) / ROWS_PER_WAVE;
    const int blocks = (waves + 3) / 4;
    seg_pool_kernel<<<blocks, 256, 0, stream>>>(x, seg, pooled, counts, N);

    // tiny output GEMM + count*bias + relu
    const int gblocks = (B + GEMM_ROWS - 1) / GEMM_ROWS;
    out_gemm_kernel<<<gblocks, 256, 0, stream>>>(pooled, Wt, b, counts, out, B);
}